// Round 7
// baseline (1097.811 us; speedup 1.0000x reference)
//
#include <hip/hip_runtime.h>
#include <hip/hip_bf16.h>

// Problem constants
#define NN 50000
#define EE 800000
#define DD 128
#define FF 16
#define LL 5
#define NB32 1563         // ceil(50000/32) row-tile blocks in GEMMs

typedef __attribute__((ext_vector_type(8))) short bf16x8;
typedef __attribute__((ext_vector_type(4))) float f32x4;
typedef __attribute__((ext_vector_type(2))) _Float16 half2_t;

__device__ __forceinline__ unsigned short f2bf(float f) {
    union { float f; unsigned int u; } v; v.f = f;
    unsigned int u = v.u;
    unsigned int r = (u + 0x7fffu + ((u >> 16) & 1u)) >> 16;
    return (unsigned short)r;
}
__device__ __forceinline__ float bf2f(unsigned short s) {
    union { unsigned int u; float f; } v; v.u = ((unsigned int)s) << 16;
    return v.f;
}
#define BFLO(u) __uint_as_float((unsigned int)(u) << 16)
#define BFHI(u) __uint_as_float((unsigned int)(u) & 0xffff0000u)

__device__ __forceinline__ half2_t u2h2(unsigned int u) {
    union { unsigned int u; half2_t h; } v; v.u = u; return v.h;
}
__device__ __forceinline__ unsigned int pkh2(float a, float b) {
    union { half2_t h; unsigned int u; } v;
    v.h[0] = (_Float16)a; v.h[1] = (_Float16)b; return v.u;
}
#if __has_builtin(__builtin_amdgcn_fdot2)
#define FDOT2(A, B, C) __builtin_amdgcn_fdot2((A), (B), (C), false)
#else
__device__ __forceinline__ float fdot2_fb(half2_t a, half2_t b, float c) {
    return (float)a[0] * (float)b[0] + (float)a[1] * (float)b[1] + c;
}
#define FDOT2(A, B, C) fdot2_fb((A), (B), (C))
#endif

// ---------------- node encoder: h = x @ W_node + b_node (+ bf16 mirror) ----------------
__global__ void k_node_enc(const float* __restrict__ x, const float* __restrict__ Wn,
                           const float* __restrict__ bn, float* __restrict__ h,
                           unsigned short* __restrict__ h_bf)
{
    const int t = blockIdx.x * 256 + threadIdx.x;   // grid exactly N*128
    const int i = t >> 7, d = t & 127;
    const float4* x4 = (const float4*)(x + (size_t)i * 16);
    float4 a0 = x4[0], a1 = x4[1], a2 = x4[2], a3 = x4[3];
    float acc = bn[d];
    acc += a0.x*Wn[0*128+d] + a0.y*Wn[1*128+d] + a0.z*Wn[2*128+d] + a0.w*Wn[3*128+d];
    acc += a1.x*Wn[4*128+d] + a1.y*Wn[5*128+d] + a1.z*Wn[6*128+d] + a1.w*Wn[7*128+d];
    acc += a2.x*Wn[8*128+d] + a2.y*Wn[9*128+d] + a2.z*Wn[10*128+d] + a2.w*Wn[11*128+d];
    acc += a3.x*Wn[12*128+d] + a3.y*Wn[13*128+d] + a3.z*Wn[14*128+d] + a3.w*Wn[15*128+d];
    h[t] = acc;
    h_bf[t] = f2bf(acc);
}

// ---------------- CSR build ----------------
__global__ void k_count(const int* __restrict__ ei, int* __restrict__ counts)
{
    const int e = blockIdx.x * 256 + threadIdx.x;   // grid exactly E
    atomicAdd(&counts[ei[EE + e]], 1);
}

__global__ __launch_bounds__(1024) void k_scan(int* __restrict__ counts, int* __restrict__ row_ptr)
{
    __shared__ int wsum[16];
    __shared__ int carry;
    const int tid = threadIdx.x, lane = tid & 63, w = tid >> 6;
    if (tid == 0) carry = 0;
    __syncthreads();
    for (int base = 0; base < NN; base += 1024) {
        const int i = base + tid;
        const int v = (i < NN) ? counts[i] : 0;
        int x = v;
        #pragma unroll
        for (int off = 1; off < 64; off <<= 1) {
            const int t = __shfl_up(x, off);
            if (lane >= off) x += t;
        }
        if (lane == 63) wsum[w] = x;
        __syncthreads();
        int woff = 0, total = 0;
        #pragma unroll
        for (int j = 0; j < 16; ++j) { const int s = wsum[j]; total += s; if (j < w) woff += s; }
        const int ex = carry + woff + x - v;
        if (i < NN) { row_ptr[i] = ex; counts[i] = ex; }
        __syncthreads();
        if (tid == 0) carry += total;
        __syncthreads();
    }
    if (tid == 0) row_ptr[NN] = carry;
}

// Fill CSR slots AND permute+convert edge features to f16 pairs in CSR order.
__global__ void k_fill(const int* __restrict__ ei, const float* __restrict__ ea,
                       int* __restrict__ cursor, int* __restrict__ src_perm,
                       unsigned int* __restrict__ ea_h)
{
    const int e = blockIdx.x * 256 + threadIdx.x;   // grid exactly E
    const int dst = ei[EE + e];
    const int p = atomicAdd(&cursor[dst], 1);
    src_perm[p] = ei[e];
    const float4* s4 = (const float4*)(ea + (size_t)e * 16);
    const float4 a0 = s4[0], a1 = s4[1], a2 = s4[2], a3 = s4[3];
    union { uint4 v[2]; unsigned int u[8]; } o;
    o.u[0] = pkh2(a0.x, a0.y); o.u[1] = pkh2(a0.z, a0.w);
    o.u[2] = pkh2(a1.x, a1.y); o.u[3] = pkh2(a1.z, a1.w);
    o.u[4] = pkh2(a2.x, a2.y); o.u[5] = pkh2(a2.z, a2.w);
    o.u[6] = pkh2(a3.x, a3.y); o.u[7] = pkh2(a3.z, a3.w);
    uint4* dp = (uint4*)(ea_h + (size_t)p * 8);
    dp[0] = o.v[0]; dp[1] = o.v[1];
}

// ---------------- weight repack to MFMA B-fragment layout ----------------
__global__ void k_pack(const float* __restrict__ W1, const float* __restrict__ W2,
                       unsigned short* __restrict__ Wp1, unsigned short* __restrict__ Wp2)
{
    int t = blockIdx.x * 256 + threadIdx.x;   // grid exactly 2*L*32768
    const int total = LL * 32768;
    if (t < total) {
        const int l = t >> 15, r = t & 32767;
        const int j = r & 7, lane = (r >> 3) & 63, kt = (r >> 9) & 3, nt = r >> 11;
        const int k = kt * 32 + (lane >> 4) * 8 + j;
        const int n = nt * 16 + (lane & 15);
        Wp1[t] = f2bf(W1[(size_t)l * 32768 + k * 256 + n]);
    } else {
        t -= total;
        const int l = t >> 15, r = t & 32767;
        const int j = r & 7, lane = (r >> 3) & 63, kt = (r >> 9) & 7, nt = r >> 12;
        const int k = kt * 32 + (lane >> 4) * 8 + j;
        const int n = nt * 16 + (lane & 15);
        Wp2[t] = f2bf(W2[(size_t)l * 32768 + k * 128 + n]);
    }
}

// ---------------- fused edge-encode + gather + aggregate + GIN-z (bf16 out) ----------------
// R6: edge-encoder dot via v_dot2_f32_f16 (2 MAC/lane/cycle) on f16 feature
// pairs; block 0 zeroes the BN stats accumulators (replaces memset launch).
__global__ __launch_bounds__(256) void k_agg(
    const unsigned short* __restrict__ h_bf, const unsigned int* __restrict__ ea_h,
    const float* __restrict__ We_l, const float* __restrict__ be_l,
    const float* __restrict__ eps_gin, const int l,
    const int* __restrict__ row_ptr, const int* __restrict__ src_perm,
    unsigned short* __restrict__ z_bf, float* __restrict__ stats)
{
    if (blockIdx.x == 0) {   // zero ps1/pq1/ps2/pq2 for this layer (768 floats)
        stats[threadIdx.x] = 0.f;
        stats[threadIdx.x + 256] = 0.f;
        stats[threadIdx.x + 512] = 0.f;
    }
    const int wv = threadIdx.x >> 6;
    const int v  = blockIdx.x * 4 + wv;      // grid exactly N/4 blocks
    const int lane = threadIdx.x & 63;
    const int c2 = lane * 2;
    half2_t wx[8], wy[8];
    #pragma unroll
    for (int j = 0; j < 8; ++j) {
        wx[j] = u2h2(pkh2(We_l[(2*j) * 128 + c2],     We_l[(2*j+1) * 128 + c2]));
        wy[j] = u2h2(pkh2(We_l[(2*j) * 128 + c2 + 1], We_l[(2*j+1) * 128 + c2 + 1]));
    }
    const float2 bed = *(const float2*)(be_l + c2);
    const float epsv = 1.0f + eps_gin[l];
    const int kbeg = __builtin_amdgcn_readfirstlane(row_ptr[v]);
    const int kend = __builtin_amdgcn_readfirstlane(row_ptr[v + 1]);
    float2 acc0 = {0.f,0.f}, acc1 = {0.f,0.f}, acc2 = {0.f,0.f}, acc3 = {0.f,0.f};

#define EDGE_DOT(EA, EB, HQ, OUT) do {                                      \
        float ex_ = bed.x, ey_ = bed.y;                                     \
        const half2_t q0_ = u2h2(EA.x), q1_ = u2h2(EA.y);                   \
        const half2_t q2_ = u2h2(EA.z), q3_ = u2h2(EA.w);                   \
        const half2_t q4_ = u2h2(EB.x), q5_ = u2h2(EB.y);                   \
        const half2_t q6_ = u2h2(EB.z), q7_ = u2h2(EB.w);                   \
        ex_ = FDOT2(q0_, wx[0], ex_); ey_ = FDOT2(q0_, wy[0], ey_);         \
        ex_ = FDOT2(q1_, wx[1], ex_); ey_ = FDOT2(q1_, wy[1], ey_);         \
        ex_ = FDOT2(q2_, wx[2], ex_); ey_ = FDOT2(q2_, wy[2], ey_);         \
        ex_ = FDOT2(q3_, wx[3], ex_); ey_ = FDOT2(q3_, wy[3], ey_);         \
        ex_ = FDOT2(q4_, wx[4], ex_); ey_ = FDOT2(q4_, wy[4], ey_);         \
        ex_ = FDOT2(q5_, wx[5], ex_); ey_ = FDOT2(q5_, wy[5], ey_);         \
        ex_ = FDOT2(q6_, wx[6], ex_); ey_ = FDOT2(q6_, wy[6], ey_);         \
        ex_ = FDOT2(q7_, wx[7], ex_); ey_ = FDOT2(q7_, wy[7], ey_);         \
        const float mx_ = BFLO(HQ) + ex_, my_ = BFHI(HQ) + ey_;             \
        OUT.x += mx_ > 0.f ? mx_ : 0.f;                                     \
        OUT.y += my_ > 0.f ? my_ : 0.f;                                     \
    } while (0)

    uint4 ce0, ce1, ce2, ce3, ce4, ce5, ce6, ce7;
    unsigned int ch0, ch1, ch2, ch3;
    int vs0, vs1, vs2, vs3;

    int k = kbeg;
    if (k < kend) {
        const int a0 = __builtin_amdgcn_readfirstlane(src_perm[k]);
        const int a1 = __builtin_amdgcn_readfirstlane(src_perm[k + 1]);
        const int a2 = __builtin_amdgcn_readfirstlane(src_perm[k + 2]);
        const int a3 = __builtin_amdgcn_readfirstlane(src_perm[k + 3]);
        ch0 = *(const unsigned int*)(h_bf + (size_t)a0 * 128 + c2);
        ch1 = *(const unsigned int*)(h_bf + (size_t)a1 * 128 + c2);
        ch2 = *(const unsigned int*)(h_bf + (size_t)a2 * 128 + c2);
        ch3 = *(const unsigned int*)(h_bf + (size_t)a3 * 128 + c2);
        const uint4* ep = (const uint4*)(ea_h + (size_t)k * 8);
        ce0 = ep[0]; ce1 = ep[1]; ce2 = ep[2]; ce3 = ep[3];
        ce4 = ep[4]; ce5 = ep[5]; ce6 = ep[6]; ce7 = ep[7];
        vs0 = src_perm[k + 4]; vs1 = src_perm[k + 5];
        vs2 = src_perm[k + 6]; vs3 = src_perm[k + 7];
    }
    for (; k < kend; k += 4) {
        const int fs0 = src_perm[k + 8],  fs1 = src_perm[k + 9];
        const int fs2 = src_perm[k + 10], fs3 = src_perm[k + 11];
        const int b0 = __builtin_amdgcn_readfirstlane(vs0);
        const int b1 = __builtin_amdgcn_readfirstlane(vs1);
        const int b2 = __builtin_amdgcn_readfirstlane(vs2);
        const int b3 = __builtin_amdgcn_readfirstlane(vs3);
        const unsigned int nh0 = *(const unsigned int*)(h_bf + (size_t)b0 * 128 + c2);
        const unsigned int nh1 = *(const unsigned int*)(h_bf + (size_t)b1 * 128 + c2);
        const unsigned int nh2 = *(const unsigned int*)(h_bf + (size_t)b2 * 128 + c2);
        const unsigned int nh3 = *(const unsigned int*)(h_bf + (size_t)b3 * 128 + c2);
        const uint4* np_ = (const uint4*)(ea_h + (size_t)(k + 4) * 8);
        const uint4 ne0 = np_[0], ne1 = np_[1], ne2 = np_[2], ne3 = np_[3];
        const uint4 ne4 = np_[4], ne5 = np_[5], ne6 = np_[6], ne7 = np_[7];
        __builtin_amdgcn_sched_barrier(0);
        EDGE_DOT(ce0, ce1, ch0, acc0);
        if (k + 1 < kend) EDGE_DOT(ce2, ce3, ch1, acc1);
        if (k + 2 < kend) EDGE_DOT(ce4, ce5, ch2, acc2);
        if (k + 3 < kend) EDGE_DOT(ce6, ce7, ch3, acc3);
        ce0=ne0; ce1=ne1; ce2=ne2; ce3=ne3; ce4=ne4; ce5=ne5; ce6=ne6; ce7=ne7;
        ch0=nh0; ch1=nh1; ch2=nh2; ch3=nh3;
        vs0=fs0; vs1=fs1; vs2=fs2; vs3=fs3;
    }
#undef EDGE_DOT
    const unsigned int hv = *(const unsigned int*)(h_bf + (size_t)v * 128 + c2);
    const float zx = epsv * BFLO(hv) + ((acc0.x + acc1.x) + (acc2.x + acc3.x));
    const float zy = epsv * BFHI(hv) + ((acc0.y + acc1.y) + (acc2.y + acc3.y));
    const unsigned int zp = (unsigned int)f2bf(zx) | ((unsigned int)f2bf(zy) << 16);
    *(unsigned int*)(z_bf + (size_t)v * 128 + c2) = zp;
}

// ---------------- GEMM1: t = z @ W1 (32-row tiles). B in registers. ----------------
__global__ __launch_bounds__(256) void k_gemmB(
    const unsigned short* __restrict__ z_bf,
    const unsigned short* __restrict__ Wp,
    unsigned short* __restrict__ t_bf,
    float* __restrict__ ps1, float* __restrict__ pq1)
{
    const int tid = threadIdx.x;
    const int w = tid >> 6, l6 = tid & 63, m = l6 & 15, quad = l6 >> 4;
    const int r0 = blockIdx.x * 32;
    const bf16x8* Wv = (const bf16x8*)Wp;
    bf16x8 b[4][4];                      // wave's 64-col B stripe, loaded once
    #pragma unroll
    for (int ct = 0; ct < 4; ++ct)
        #pragma unroll
        for (int kt = 0; kt < 4; ++kt)
            b[ct][kt] = Wv[((w * 4 + ct) * 4 + kt) * 64 + l6];

    const bf16x8 zero8 = {0,0,0,0,0,0,0,0};
    const f32x4 z4 = {0.f, 0.f, 0.f, 0.f};
    float rs_[4] = {0.f,0.f,0.f,0.f}, rq_[4] = {0.f,0.f,0.f,0.f};

    bf16x8 a[4], an[4];
    {
        const int row = r0 + m;
        #pragma unroll
        for (int kt = 0; kt < 4; ++kt)
            a[kt] = (row < NN) ? *(const bf16x8*)(z_bf + (size_t)row * 128 + kt * 32 + quad * 8) : zero8;
    }
    #pragma unroll
    for (int rt = 0; rt < 2; ++rt) {
        if (rt < 1) {
            const int row = r0 + 16 + m;
            #pragma unroll
            for (int kt = 0; kt < 4; ++kt)
                an[kt] = (row < NN) ? *(const bf16x8*)(z_bf + (size_t)row * 128 + kt * 32 + quad * 8) : zero8;
        }
        f32x4 acc[4] = {z4, z4, z4, z4};
        #pragma unroll
        for (int kt = 0; kt < 4; ++kt)
            #pragma unroll
            for (int ct = 0; ct < 4; ++ct)
                acc[ct] = __builtin_amdgcn_mfma_f32_16x16x32_bf16(a[kt], b[ct][kt], acc[ct], 0, 0, 0);
        const int rowb = r0 + rt * 16 + quad * 4;
        #pragma unroll
        for (int ct = 0; ct < 4; ++ct) {
            const int col = w * 64 + ct * 16 + m;
            #pragma unroll
            for (int r = 0; r < 4; ++r) {
                const float val = acc[ct][r];
                if (rowb + r < NN) t_bf[(size_t)(rowb + r) * 256 + col] = f2bf(val);
                rs_[ct] += val; rq_[ct] += val * val;
            }
        }
        #pragma unroll
        for (int kt = 0; kt < 4; ++kt) a[kt] = an[kt];
    }
    #pragma unroll
    for (int ct = 0; ct < 4; ++ct) {
        float ss = rs_[ct], sq = rq_[ct];
        ss += __shfl_xor(ss, 16); ss += __shfl_xor(ss, 32);
        sq += __shfl_xor(sq, 16); sq += __shfl_xor(sq, 32);
        if (quad == 0) {
            const int col = w * 64 + ct * 16 + m;
            atomicAdd(&ps1[col], ss);
            atomicAdd(&pq1[col], sq);
        }
    }
}

// ---------------- GEMM2: v = relu(BN1(t)) @ W2 (32-row tiles). BN folded in-block. ----------------
__global__ __launch_bounds__(256) void k_gemmD(
    const unsigned short* __restrict__ t_bf,
    const float* __restrict__ ps1, const float* __restrict__ pq1,
    const float* __restrict__ g1, const float* __restrict__ be1,
    const unsigned short* __restrict__ Wp,
    unsigned short* __restrict__ vb,
    float* __restrict__ ps2, float* __restrict__ pq2)
{
    __shared__ __align__(16) unsigned short us[32 * 264];
    __shared__ __align__(16) float scf[256], shf[256];
    const int tid = threadIdx.x;
    {   // fold global column sums -> scale/shift (256 threads, 1 col each)
        const float mean = ps1[tid] * (1.0f / NN);
        const float var  = pq1[tid] * (1.0f / NN) - mean * mean;
        const float sc = g1[tid] * rsqrtf(var + 1e-5f);
        scf[tid] = sc;
        shf[tid] = be1[tid] - mean * sc;
    }
    __syncthreads();
    const int r0 = blockIdx.x * 32;
    {
        const int rb = tid >> 5, c0 = (tid & 31) * 8;
        const float4 s0 = *(const float4*)(scf + c0), s1 = *(const float4*)(scf + c0 + 4);
        const float4 b0 = *(const float4*)(shf + c0), b1 = *(const float4*)(shf + c0 + 4);
        const bf16x8 zero = {0,0,0,0,0,0,0,0};
        #pragma unroll
        for (int rr = 0; rr < 4; ++rr) {
            const int row = rr * 8 + rb, g = r0 + row;
            union { bf16x8 v; unsigned short u[8]; } in, o;
            if (g < NN) {
                in.v = *(const bf16x8*)(t_bf + (size_t)g * 256 + c0);
                float xv;
                xv = bf2f(in.u[0])*s0.x + b0.x; o.u[0] = f2bf(xv > 0.f ? xv : 0.f);
                xv = bf2f(in.u[1])*s0.y + b0.y; o.u[1] = f2bf(xv > 0.f ? xv : 0.f);
                xv = bf2f(in.u[2])*s0.z + b0.z; o.u[2] = f2bf(xv > 0.f ? xv : 0.f);
                xv = bf2f(in.u[3])*s0.w + b0.w; o.u[3] = f2bf(xv > 0.f ? xv : 0.f);
                xv = bf2f(in.u[4])*s1.x + b1.x; o.u[4] = f2bf(xv > 0.f ? xv : 0.f);
                xv = bf2f(in.u[5])*s1.y + b1.y; o.u[5] = f2bf(xv > 0.f ? xv : 0.f);
                xv = bf2f(in.u[6])*s1.z + b1.z; o.u[6] = f2bf(xv > 0.f ? xv : 0.f);
                xv = bf2f(in.u[7])*s1.w + b1.w; o.u[7] = f2bf(xv > 0.f ? xv : 0.f);
            } else {
                o.v = zero;
            }
            *(bf16x8*)(&us[row * 264 + c0]) = o.v;
        }
    }
    __syncthreads();
    const int w = tid >> 6, l6 = tid & 63, m = l6 & 15, quad = l6 >> 4;
    const bf16x8* Wv = (const bf16x8*)Wp;
    bf16x8 b[2][8];                      // wave's 32-col B stripe
    #pragma unroll
    for (int ct = 0; ct < 2; ++ct)
        #pragma unroll
        for (int kt = 0; kt < 8; ++kt)
            b[ct][kt] = Wv[((w * 2 + ct) * 8 + kt) * 64 + l6];

    const f32x4 z4 = {0.f, 0.f, 0.f, 0.f};
    float rs_[2] = {0.f,0.f}, rq_[2] = {0.f,0.f};
    #pragma unroll
    for (int rt = 0; rt < 2; ++rt) {
        bf16x8 a[8];
        #pragma unroll
        for (int kt = 0; kt < 8; ++kt)
            a[kt] = *(const bf16x8*)(&us[(rt * 16 + m) * 264 + kt * 32 + quad * 8]);
        f32x4 acc[2] = {z4, z4};
        #pragma unroll
        for (int kt = 0; kt < 8; ++kt)
            #pragma unroll
            for (int ct = 0; ct < 2; ++ct)
                acc[ct] = __builtin_amdgcn_mfma_f32_16x16x32_bf16(a[kt], b[ct][kt], acc[ct], 0, 0, 0);
        const int rowb = r0 + rt * 16 + quad * 4;
        #pragma unroll
        for (int ct = 0; ct < 2; ++ct) {
            const int col = w * 32 + ct * 16 + m;
            #pragma unroll
            for (int r = 0; r < 4; ++r) {
                const float val = acc[ct][r];
                if (rowb + r < NN) vb[(size_t)(rowb + r) * 128 + col] = f2bf(val);
                rs_[ct] += val; rq_[ct] += val * val;
            }
        }
    }
    #pragma unroll
    for (int ct = 0; ct < 2; ++ct) {
        float ss = rs_[ct], sq = rq_[ct];
        ss += __shfl_xor(ss, 16); ss += __shfl_xor(ss, 32);
        sq += __shfl_xor(sq, 16); sq += __shfl_xor(sq, 32);
        if (quad == 0) {
            const int col = w * 32 + ct * 16 + m;
            atomicAdd(&ps2[col], ss);
            atomicAdd(&pq2[col], sq);
        }
    }
}

// ---------------- BN2 + optional relu + residual (+ bf16 mirror), 8 ch/thread ----------------
__global__ void k_fin(const unsigned short* __restrict__ vb,
                      const float* __restrict__ ps2, const float* __restrict__ pq2,
                      const float* __restrict__ g2, const float* __restrict__ be2,
                      float* __restrict__ h, unsigned short* __restrict__ h_bf,
                      const int do_relu)
{
    __shared__ __align__(16) float scf[128], shf[128];
    const int tid = threadIdx.x;
    if (tid < 128) {
        const float mean = ps2[tid] * (1.0f / NN);
        const float var  = pq2[tid] * (1.0f / NN) - mean * mean;
        const float sc = g2[tid] * rsqrtf(var + 1e-5f);
        scf[tid] = sc;
        shf[tid] = be2[tid] - mean * sc;
    }
    __syncthreads();
    const int t = blockIdx.x * 256 + tid;   // grid exactly N*128/8
    const int base = t * 8;
    const int c = base & 127;
    union { bf16x8 v; unsigned short u[8]; } in, ob;
    in.v = *(const bf16x8*)(vb + base);
    const float4 s0 = *(const float4*)(scf + c), s1 = *(const float4*)(scf + c + 4);
    const float4 b0 = *(const float4*)(shf + c), b1 = *(const float4*)(shf + c + 4);
    float4 h0 = *(const float4*)(h + base), h1 = *(const float4*)(h + base + 4);
    float z;
    z = bf2f(in.u[0])*s0.x + b0.x; if (do_relu) z = z > 0.f ? z : 0.f; h0.x += z;
    z = bf2f(in.u[1])*s0.y + b0.y; if (do_relu) z = z > 0.f ? z : 0.f; h0.y += z;
    z = bf2f(in.u[2])*s0.z + b0.z; if (do_relu) z = z > 0.f ? z : 0.f; h0.z += z;
    z = bf2f(in.u[3])*s0.w + b0.w; if (do_relu) z = z > 0.f ? z : 0.f; h0.w += z;
    z = bf2f(in.u[4])*s1.x + b1.x; if (do_relu) z = z > 0.f ? z : 0.f; h1.x += z;
    z = bf2f(in.u[5])*s1.y + b1.y; if (do_relu) z = z > 0.f ? z : 0.f; h1.y += z;
    z = bf2f(in.u[6])*s1.z + b1.z; if (do_relu) z = z > 0.f ? z : 0.f; h1.z += z;
    z = bf2f(in.u[7])*s1.w + b1.w; if (do_relu) z = z > 0.f ? z : 0.f; h1.w += z;
    *(float4*)(h + base) = h0;
    *(float4*)(h + base + 4) = h1;
    ob.u[0]=f2bf(h0.x); ob.u[1]=f2bf(h0.y); ob.u[2]=f2bf(h0.z); ob.u[3]=f2bf(h0.w);
    ob.u[4]=f2bf(h1.x); ob.u[5]=f2bf(h1.y); ob.u[6]=f2bf(h1.z); ob.u[7]=f2bf(h1.w);
    *(bf16x8*)(h_bf + base) = ob.v;
}

extern "C" void kernel_launch(void* const* d_in, const int* in_sizes, int n_in,
                              void* d_out, int out_size, void* d_ws, size_t ws_size,
                              hipStream_t stream)
{
    const float* x       = (const float*)d_in[0];
    const int*   ei      = (const int*)  d_in[1];
    const float* ea      = (const float*)d_in[2];
    const float* W_node  = (const float*)d_in[3];
    const float* b_node  = (const float*)d_in[4];
    const float* We      = (const float*)d_in[5];
    const float* be      = (const float*)d_in[6];
    const float* eps_gin = (const float*)d_in[7];
    const float* W1      = (const float*)d_in[8];
    // d_in[9] = b1: cancels exactly under BN1 (mean subtraction)
    const float* g1      = (const float*)d_in[10];
    const float* beta1   = (const float*)d_in[11];
    const float* W2      = (const float*)d_in[12];
    // d_in[13] = b2: cancels exactly under BN2
    const float* g_bn    = (const float*)d_in[14];
    const float* beta_bn = (const float*)d_in[15];

    float* h = (float*)d_out;

    char* W = (char*)d_ws;
    int*   counts   = (int*)  (W + 0);             // 200000 B (also fill cursor)
    int*   row_ptr  = (int*)  (W + 200000);        // 200004 B → pad to 400064
    float* stats    = (float*)(W + 400064);        // 768 floats = 3072 B
    float* ps1 = stats, *pq1 = stats + 256, *ps2 = stats + 512, *pq2 = stats + 640;
    int*   src_perm = (int*)  (W + 403136);        // (EE+16)*4 = 3200064 B
    unsigned int* ea_h   = (unsigned int*)(W + 3603200);    // EE*32+512 = 25600512 B
    unsigned short* Wp1  = (unsigned short*)(W + 29203712); // 327680 B
    unsigned short* Wp2  = (unsigned short*)(W + 29531392); // 327680 B
    unsigned short* z_bf = (unsigned short*)(W + 29859072); // 12800000 B (vb alias)
    unsigned short* t_bf = (unsigned short*)(W + 42659072); // 25600000 B
    unsigned short* h_bf = (unsigned short*)(W + 68259072); // 12800000 B → total ~81.1 MB
    unsigned short* vb   = z_bf;  // safe alias: z_bf dead after gemmB, vb born in gemmD

    (void)hipMemsetAsync(counts, 0, 200000, stream);
    (void)hipMemsetAsync(src_perm + EE, 0, 64, stream);   // pipeline overrun pad

    k_node_enc<<<dim3(NN * DD / 256), dim3(256), 0, stream>>>(x, W_node, b_node, h, h_bf);
    k_count<<<dim3(EE / 256), dim3(256), 0, stream>>>(ei, counts);
    k_scan<<<dim3(1), dim3(1024), 0, stream>>>(counts, row_ptr);
    k_fill<<<dim3(EE / 256), dim3(256), 0, stream>>>(ei, ea, counts, src_perm, ea_h);
    k_pack<<<dim3(2 * LL * 32768 / 256), dim3(256), 0, stream>>>(W1, W2, Wp1, Wp2);

    for (int l = 0; l < LL; ++l) {
        k_agg<<<dim3(NN / 4), dim3(256), 0, stream>>>(
            h_bf, ea_h, We + (size_t)l * FF * DD, be + (size_t)l * DD,
            eps_gin, l, row_ptr, src_perm, z_bf, stats);
        k_gemmB<<<dim3(NB32), dim3(256), 0, stream>>>(
            z_bf, Wp1 + (size_t)l * 32768, t_bf, ps1, pq1);
        k_gemmD<<<dim3(NB32), dim3(256), 0, stream>>>(
            t_bf, ps1, pq1, g1 + (size_t)l * 256, beta1 + (size_t)l * 256,
            Wp2 + (size_t)l * 32768, vb, ps2, pq2);
        k_fin<<<dim3(NN * DD / 8 / 256), dim3(256), 0, stream>>>(
            vb, ps2, pq2, g_bn + (size_t)l * 128, beta_bn + (size_t)l * 128,
            h, h_bf, (l < LL - 1) ? 1 : 0);
    }
}

// Round 8
// 903.411 us; speedup vs baseline: 1.2152x; 1.2152x over previous
//
#include <hip/hip_runtime.h>
#include <hip/hip_bf16.h>

// Problem constants
#define NN 50000
#define EE 800000
#define DD 128
#define FF 16
#define LL 5
#define NB 782            // ceil(50000/64) row-tile blocks in GEMMs (64-row: best measured)

typedef __attribute__((ext_vector_type(8))) short bf16x8;
typedef __attribute__((ext_vector_type(4))) float f32x4;
typedef __attribute__((ext_vector_type(2))) _Float16 half2_t;

__device__ __forceinline__ unsigned short f2bf(float f) {
    union { float f; unsigned int u; } v; v.f = f;
    unsigned int u = v.u;
    unsigned int r = (u + 0x7fffu + ((u >> 16) & 1u)) >> 16;
    return (unsigned short)r;
}
__device__ __forceinline__ float bf2f(unsigned short s) {
    union { unsigned int u; float f; } v; v.u = ((unsigned int)s) << 16;
    return v.f;
}
#define BFLO(u) __uint_as_float((unsigned int)(u) << 16)
#define BFHI(u) __uint_as_float((unsigned int)(u) & 0xffff0000u)

__device__ __forceinline__ half2_t u2h2(unsigned int u) {
    union { unsigned int u; half2_t h; } v; v.u = u; return v.h;
}
__device__ __forceinline__ unsigned int pkh2(float a, float b) {
    union { half2_t h; unsigned int u; } v;
    v.h[0] = (_Float16)a; v.h[1] = (_Float16)b; return v.u;
}
#if __has_builtin(__builtin_amdgcn_fdot2)
#define FDOT2(A, B, C) __builtin_amdgcn_fdot2((A), (B), (C), false)
#else
__device__ __forceinline__ float fdot2_fb(half2_t a, half2_t b, float c) {
    return (float)a[0] * (float)b[0] + (float)a[1] * (float)b[1] + c;
}
#define FDOT2(A, B, C) fdot2_fb((A), (B), (C))
#endif

// ---------------- node encoder: h = x @ W_node + b_node (+ bf16 mirror) ----------------
__global__ void k_node_enc(const float* __restrict__ x, const float* __restrict__ Wn,
                           const float* __restrict__ bn, float* __restrict__ h,
                           unsigned short* __restrict__ h_bf)
{
    const int t = blockIdx.x * 256 + threadIdx.x;   // grid exactly N*128
    const int i = t >> 7, d = t & 127;
    const float4* x4 = (const float4*)(x + (size_t)i * 16);
    float4 a0 = x4[0], a1 = x4[1], a2 = x4[2], a3 = x4[3];
    float acc = bn[d];
    acc += a0.x*Wn[0*128+d] + a0.y*Wn[1*128+d] + a0.z*Wn[2*128+d] + a0.w*Wn[3*128+d];
    acc += a1.x*Wn[4*128+d] + a1.y*Wn[5*128+d] + a1.z*Wn[6*128+d] + a1.w*Wn[7*128+d];
    acc += a2.x*Wn[8*128+d] + a2.y*Wn[9*128+d] + a2.z*Wn[10*128+d] + a2.w*Wn[11*128+d];
    acc += a3.x*Wn[12*128+d] + a3.y*Wn[13*128+d] + a3.z*Wn[14*128+d] + a3.w*Wn[15*128+d];
    h[t] = acc;
    h_bf[t] = f2bf(acc);
}

// ---------------- CSR build ----------------
__global__ void k_count(const int* __restrict__ ei, int* __restrict__ counts)
{
    const int e = blockIdx.x * 256 + threadIdx.x;   // grid exactly E
    atomicAdd(&counts[ei[EE + e]], 1);
}

__global__ __launch_bounds__(1024) void k_scan(int* __restrict__ counts, int* __restrict__ row_ptr)
{
    __shared__ int wsum[16];
    __shared__ int carry;
    const int tid = threadIdx.x, lane = tid & 63, w = tid >> 6;
    if (tid == 0) carry = 0;
    __syncthreads();
    for (int base = 0; base < NN; base += 1024) {
        const int i = base + tid;
        const int v = (i < NN) ? counts[i] : 0;
        int x = v;
        #pragma unroll
        for (int off = 1; off < 64; off <<= 1) {
            const int t = __shfl_up(x, off);
            if (lane >= off) x += t;
        }
        if (lane == 63) wsum[w] = x;
        __syncthreads();
        int woff = 0, total = 0;
        #pragma unroll
        for (int j = 0; j < 16; ++j) { const int s = wsum[j]; total += s; if (j < w) woff += s; }
        const int ex = carry + woff + x - v;
        if (i < NN) { row_ptr[i] = ex; counts[i] = ex; }
        __syncthreads();
        if (tid == 0) carry += total;
        __syncthreads();
    }
    if (tid == 0) row_ptr[NN] = carry;
}

// R7 phase 1: scatter only 8B/edge (slot assignment). No feature movement.
__global__ void k_fill1(const int* __restrict__ ei, int* __restrict__ cursor,
                        int2* __restrict__ esrc)
{
    const int e = blockIdx.x * 256 + threadIdx.x;   // grid exactly E
    const int dst = ei[EE + e];
    const int p = atomicAdd(&cursor[dst], 1);
    esrc[p] = make_int2(e, ei[e]);
}

// R7 phase 2: sequential over CSR slots — gather ea[e] (random read, no RMW),
// write ea_h + src_perm fully coalesced.
__global__ void k_fill2(const int2* __restrict__ esrc, const float* __restrict__ ea,
                        int* __restrict__ src_perm, unsigned int* __restrict__ ea_h)
{
    const int p = blockIdx.x * 256 + threadIdx.x;   // grid exactly E
    const int2 es = esrc[p];
    src_perm[p] = es.y;
    const float4* s4 = (const float4*)(ea + (size_t)es.x * 16);
    const float4 a0 = s4[0], a1 = s4[1], a2 = s4[2], a3 = s4[3];
    union { uint4 v[2]; unsigned int u[8]; } o;
    o.u[0] = pkh2(a0.x, a0.y); o.u[1] = pkh2(a0.z, a0.w);
    o.u[2] = pkh2(a1.x, a1.y); o.u[3] = pkh2(a1.z, a1.w);
    o.u[4] = pkh2(a2.x, a2.y); o.u[5] = pkh2(a2.z, a2.w);
    o.u[6] = pkh2(a3.x, a3.y); o.u[7] = pkh2(a3.z, a3.w);
    uint4* dp = (uint4*)(ea_h + (size_t)p * 8);
    dp[0] = o.v[0]; dp[1] = o.v[1];
}

// ---------------- weight repack to MFMA B-fragment layout ----------------
__global__ void k_pack(const float* __restrict__ W1, const float* __restrict__ W2,
                       unsigned short* __restrict__ Wp1, unsigned short* __restrict__ Wp2)
{
    int t = blockIdx.x * 256 + threadIdx.x;   // grid exactly 2*L*32768
    const int total = LL * 32768;
    if (t < total) {
        const int l = t >> 15, r = t & 32767;
        const int j = r & 7, lane = (r >> 3) & 63, kt = (r >> 9) & 3, nt = r >> 11;
        const int k = kt * 32 + (lane >> 4) * 8 + j;
        const int n = nt * 16 + (lane & 15);
        Wp1[t] = f2bf(W1[(size_t)l * 32768 + k * 256 + n]);
    } else {
        t -= total;
        const int l = t >> 15, r = t & 32767;
        const int j = r & 7, lane = (r >> 3) & 63, kt = (r >> 9) & 7, nt = r >> 12;
        const int k = kt * 32 + (lane >> 4) * 8 + j;
        const int n = nt * 16 + (lane & 15);
        Wp2[t] = f2bf(W2[(size_t)l * 32768 + k * 128 + n]);
    }
}

// ---------------- fused edge-encode + gather + aggregate + GIN-z (bf16 out) ----------------
// fdot2 edge-encoder (R6, kept); block 0 zeroes BN stats accumulators.
__global__ __launch_bounds__(256) void k_agg(
    const unsigned short* __restrict__ h_bf, const unsigned int* __restrict__ ea_h,
    const float* __restrict__ We_l, const float* __restrict__ be_l,
    const float* __restrict__ eps_gin, const int l,
    const int* __restrict__ row_ptr, const int* __restrict__ src_perm,
    unsigned short* __restrict__ z_bf, float* __restrict__ stats)
{
    if (blockIdx.x == 0) {   // zero ps1/pq1/ps2/pq2 for this layer (768 floats)
        stats[threadIdx.x] = 0.f;
        stats[threadIdx.x + 256] = 0.f;
        stats[threadIdx.x + 512] = 0.f;
    }
    const int wv = threadIdx.x >> 6;
    const int v  = blockIdx.x * 4 + wv;      // grid exactly N/4 blocks
    const int lane = threadIdx.x & 63;
    const int c2 = lane * 2;
    half2_t wx[8], wy[8];
    #pragma unroll
    for (int j = 0; j < 8; ++j) {
        wx[j] = u2h2(pkh2(We_l[(2*j) * 128 + c2],     We_l[(2*j+1) * 128 + c2]));
        wy[j] = u2h2(pkh2(We_l[(2*j) * 128 + c2 + 1], We_l[(2*j+1) * 128 + c2 + 1]));
    }
    const float2 bed = *(const float2*)(be_l + c2);
    const float epsv = 1.0f + eps_gin[l];
    const int kbeg = __builtin_amdgcn_readfirstlane(row_ptr[v]);
    const int kend = __builtin_amdgcn_readfirstlane(row_ptr[v + 1]);
    float2 acc0 = {0.f,0.f}, acc1 = {0.f,0.f}, acc2 = {0.f,0.f}, acc3 = {0.f,0.f};

#define EDGE_DOT(EA, EB, HQ, OUT) do {                                      \
        float ex_ = bed.x, ey_ = bed.y;                                     \
        const half2_t q0_ = u2h2(EA.x), q1_ = u2h2(EA.y);                   \
        const half2_t q2_ = u2h2(EA.z), q3_ = u2h2(EA.w);                   \
        const half2_t q4_ = u2h2(EB.x), q5_ = u2h2(EB.y);                   \
        const half2_t q6_ = u2h2(EB.z), q7_ = u2h2(EB.w);                   \
        ex_ = FDOT2(q0_, wx[0], ex_); ey_ = FDOT2(q0_, wy[0], ey_);         \
        ex_ = FDOT2(q1_, wx[1], ex_); ey_ = FDOT2(q1_, wy[1], ey_);         \
        ex_ = FDOT2(q2_, wx[2], ex_); ey_ = FDOT2(q2_, wy[2], ey_);         \
        ex_ = FDOT2(q3_, wx[3], ex_); ey_ = FDOT2(q3_, wy[3], ey_);         \
        ex_ = FDOT2(q4_, wx[4], ex_); ey_ = FDOT2(q4_, wy[4], ey_);         \
        ex_ = FDOT2(q5_, wx[5], ex_); ey_ = FDOT2(q5_, wy[5], ey_);         \
        ex_ = FDOT2(q6_, wx[6], ex_); ey_ = FDOT2(q6_, wy[6], ey_);         \
        ex_ = FDOT2(q7_, wx[7], ex_); ey_ = FDOT2(q7_, wy[7], ey_);         \
        const float mx_ = BFLO(HQ) + ex_, my_ = BFHI(HQ) + ey_;             \
        OUT.x += mx_ > 0.f ? mx_ : 0.f;                                     \
        OUT.y += my_ > 0.f ? my_ : 0.f;                                     \
    } while (0)

    uint4 ce0, ce1, ce2, ce3, ce4, ce5, ce6, ce7;
    unsigned int ch0, ch1, ch2, ch3;
    int vs0, vs1, vs2, vs3;

    int k = kbeg;
    if (k < kend) {
        const int a0 = __builtin_amdgcn_readfirstlane(src_perm[k]);
        const int a1 = __builtin_amdgcn_readfirstlane(src_perm[k + 1]);
        const int a2 = __builtin_amdgcn_readfirstlane(src_perm[k + 2]);
        const int a3 = __builtin_amdgcn_readfirstlane(src_perm[k + 3]);
        ch0 = *(const unsigned int*)(h_bf + (size_t)a0 * 128 + c2);
        ch1 = *(const unsigned int*)(h_bf + (size_t)a1 * 128 + c2);
        ch2 = *(const unsigned int*)(h_bf + (size_t)a2 * 128 + c2);
        ch3 = *(const unsigned int*)(h_bf + (size_t)a3 * 128 + c2);
        const uint4* ep = (const uint4*)(ea_h + (size_t)k * 8);
        ce0 = ep[0]; ce1 = ep[1]; ce2 = ep[2]; ce3 = ep[3];
        ce4 = ep[4]; ce5 = ep[5]; ce6 = ep[6]; ce7 = ep[7];
        vs0 = src_perm[k + 4]; vs1 = src_perm[k + 5];
        vs2 = src_perm[k + 6]; vs3 = src_perm[k + 7];
    }
    for (; k < kend; k += 4) {
        const int fs0 = src_perm[k + 8],  fs1 = src_perm[k + 9];
        const int fs2 = src_perm[k + 10], fs3 = src_perm[k + 11];
        const int b0 = __builtin_amdgcn_readfirstlane(vs0);
        const int b1 = __builtin_amdgcn_readfirstlane(vs1);
        const int b2 = __builtin_amdgcn_readfirstlane(vs2);
        const int b3 = __builtin_amdgcn_readfirstlane(vs3);
        const unsigned int nh0 = *(const unsigned int*)(h_bf + (size_t)b0 * 128 + c2);
        const unsigned int nh1 = *(const unsigned int*)(h_bf + (size_t)b1 * 128 + c2);
        const unsigned int nh2 = *(const unsigned int*)(h_bf + (size_t)b2 * 128 + c2);
        const unsigned int nh3 = *(const unsigned int*)(h_bf + (size_t)b3 * 128 + c2);
        const uint4* np_ = (const uint4*)(ea_h + (size_t)(k + 4) * 8);
        const uint4 ne0 = np_[0], ne1 = np_[1], ne2 = np_[2], ne3 = np_[3];
        const uint4 ne4 = np_[4], ne5 = np_[5], ne6 = np_[6], ne7 = np_[7];
        __builtin_amdgcn_sched_barrier(0);
        EDGE_DOT(ce0, ce1, ch0, acc0);
        if (k + 1 < kend) EDGE_DOT(ce2, ce3, ch1, acc1);
        if (k + 2 < kend) EDGE_DOT(ce4, ce5, ch2, acc2);
        if (k + 3 < kend) EDGE_DOT(ce6, ce7, ch3, acc3);
        ce0=ne0; ce1=ne1; ce2=ne2; ce3=ne3; ce4=ne4; ce5=ne5; ce6=ne6; ce7=ne7;
        ch0=nh0; ch1=nh1; ch2=nh2; ch3=nh3;
        vs0=fs0; vs1=fs1; vs2=fs2; vs3=fs3;
    }
#undef EDGE_DOT
    const unsigned int hv = *(const unsigned int*)(h_bf + (size_t)v * 128 + c2);
    const float zx = epsv * BFLO(hv) + ((acc0.x + acc1.x) + (acc2.x + acc3.x));
    const float zy = epsv * BFHI(hv) + ((acc0.y + acc1.y) + (acc2.y + acc3.y));
    const unsigned int zp = (unsigned int)f2bf(zx) | ((unsigned int)f2bf(zy) << 16);
    *(unsigned int*)(z_bf + (size_t)v * 128 + c2) = zp;
}

// ---------------- GEMM1: t = z @ W1 (64-row tiles, B in registers) ----------------
__global__ __launch_bounds__(256) void k_gemmB(
    const unsigned short* __restrict__ z_bf,
    const unsigned short* __restrict__ Wp,
    unsigned short* __restrict__ t_bf,
    float* __restrict__ ps1, float* __restrict__ pq1)
{
    const int tid = threadIdx.x;
    const int w = tid >> 6, l6 = tid & 63, m = l6 & 15, quad = l6 >> 4;
    const int r0 = blockIdx.x * 64;
    const bf16x8* Wv = (const bf16x8*)Wp;
    bf16x8 b[4][4];                      // wave's B stripe, loaded once
    #pragma unroll
    for (int ct = 0; ct < 4; ++ct)
        #pragma unroll
        for (int kt = 0; kt < 4; ++kt)
            b[ct][kt] = Wv[((w * 4 + ct) * 4 + kt) * 64 + l6];

    const bf16x8 zero8 = {0,0,0,0,0,0,0,0};
    const f32x4 z4 = {0.f, 0.f, 0.f, 0.f};
    float rs_[4] = {0.f,0.f,0.f,0.f}, rq_[4] = {0.f,0.f,0.f,0.f};

    bf16x8 a[4], an[4];
    {
        const int row = r0 + m;
        #pragma unroll
        for (int kt = 0; kt < 4; ++kt)
            a[kt] = (row < NN) ? *(const bf16x8*)(z_bf + (size_t)row * 128 + kt * 32 + quad * 8) : zero8;
    }
    #pragma unroll
    for (int rt = 0; rt < 4; ++rt) {
        if (rt < 3) {
            const int row = r0 + (rt + 1) * 16 + m;
            #pragma unroll
            for (int kt = 0; kt < 4; ++kt)
                an[kt] = (row < NN) ? *(const bf16x8*)(z_bf + (size_t)row * 128 + kt * 32 + quad * 8) : zero8;
        }
        f32x4 acc[4] = {z4, z4, z4, z4};
        #pragma unroll
        for (int kt = 0; kt < 4; ++kt)
            #pragma unroll
            for (int ct = 0; ct < 4; ++ct)
                acc[ct] = __builtin_amdgcn_mfma_f32_16x16x32_bf16(a[kt], b[ct][kt], acc[ct], 0, 0, 0);
        const int rowb = r0 + rt * 16 + quad * 4;
        #pragma unroll
        for (int ct = 0; ct < 4; ++ct) {
            const int col = w * 64 + ct * 16 + m;
            #pragma unroll
            for (int r = 0; r < 4; ++r) {
                const float val = acc[ct][r];
                if (rowb + r < NN) t_bf[(size_t)(rowb + r) * 256 + col] = f2bf(val);
                rs_[ct] += val; rq_[ct] += val * val;
            }
        }
        #pragma unroll
        for (int kt = 0; kt < 4; ++kt) a[kt] = an[kt];
    }
    #pragma unroll
    for (int ct = 0; ct < 4; ++ct) {
        float ss = rs_[ct], sq = rq_[ct];
        ss += __shfl_xor(ss, 16); ss += __shfl_xor(ss, 32);
        sq += __shfl_xor(sq, 16); sq += __shfl_xor(sq, 32);
        if (quad == 0) {
            const int col = w * 64 + ct * 16 + m;
            atomicAdd(&ps1[col], ss);
            atomicAdd(&pq1[col], sq);
        }
    }
}

// ---------------- GEMM2: v = relu(BN1(t)) @ W2 (64-row tiles). BN folded in-block. ----------------
__global__ __launch_bounds__(256) void k_gemmD(
    const unsigned short* __restrict__ t_bf,
    const float* __restrict__ ps1, const float* __restrict__ pq1,
    const float* __restrict__ g1, const float* __restrict__ be1,
    const unsigned short* __restrict__ Wp,
    unsigned short* __restrict__ vb,
    float* __restrict__ ps2, float* __restrict__ pq2)
{
    __shared__ __align__(16) unsigned short us[64 * 264];
    __shared__ __align__(16) float scf[256], shf[256];
    const int tid = threadIdx.x;
    {   // fold global column sums -> scale/shift (256 threads, 1 col each)
        const float mean = ps1[tid] * (1.0f / NN);
        const float var  = pq1[tid] * (1.0f / NN) - mean * mean;
        const float sc = g1[tid] * rsqrtf(var + 1e-5f);
        scf[tid] = sc;
        shf[tid] = be1[tid] - mean * sc;
    }
    __syncthreads();
    const int r0 = blockIdx.x * 64;
    {
        const int rb = tid >> 5, c0 = (tid & 31) * 8;
        const float4 s0 = *(const float4*)(scf + c0), s1 = *(const float4*)(scf + c0 + 4);
        const float4 b0 = *(const float4*)(shf + c0), b1 = *(const float4*)(shf + c0 + 4);
        const bf16x8 zero = {0,0,0,0,0,0,0,0};
        #pragma unroll
        for (int rr = 0; rr < 8; ++rr) {
            const int row = rr * 8 + rb, g = r0 + row;
            union { bf16x8 v; unsigned short u[8]; } in, o;
            if (g < NN) {
                in.v = *(const bf16x8*)(t_bf + (size_t)g * 256 + c0);
                float xv;
                xv = bf2f(in.u[0])*s0.x + b0.x; o.u[0] = f2bf(xv > 0.f ? xv : 0.f);
                xv = bf2f(in.u[1])*s0.y + b0.y; o.u[1] = f2bf(xv > 0.f ? xv : 0.f);
                xv = bf2f(in.u[2])*s0.z + b0.z; o.u[2] = f2bf(xv > 0.f ? xv : 0.f);
                xv = bf2f(in.u[3])*s0.w + b0.w; o.u[3] = f2bf(xv > 0.f ? xv : 0.f);
                xv = bf2f(in.u[4])*s1.x + b1.x; o.u[4] = f2bf(xv > 0.f ? xv : 0.f);
                xv = bf2f(in.u[5])*s1.y + b1.y; o.u[5] = f2bf(xv > 0.f ? xv : 0.f);
                xv = bf2f(in.u[6])*s1.z + b1.z; o.u[6] = f2bf(xv > 0.f ? xv : 0.f);
                xv = bf2f(in.u[7])*s1.w + b1.w; o.u[7] = f2bf(xv > 0.f ? xv : 0.f);
            } else {
                o.v = zero;
            }
            *(bf16x8*)(&us[row * 264 + c0]) = o.v;
        }
    }
    __syncthreads();
    const int w = tid >> 6, l6 = tid & 63, m = l6 & 15, quad = l6 >> 4;
    const bf16x8* Wv = (const bf16x8*)Wp;
    bf16x8 b[2][8];                      // wave's 32-col B stripe
    #pragma unroll
    for (int ct = 0; ct < 2; ++ct)
        #pragma unroll
        for (int kt = 0; kt < 8; ++kt)
            b[ct][kt] = Wv[((w * 2 + ct) * 8 + kt) * 64 + l6];

    const f32x4 z4 = {0.f, 0.f, 0.f, 0.f};
    float rs_[2] = {0.f,0.f}, rq_[2] = {0.f,0.f};
    #pragma unroll
    for (int rt = 0; rt < 4; ++rt) {
        bf16x8 a[8];
        #pragma unroll
        for (int kt = 0; kt < 8; ++kt)
            a[kt] = *(const bf16x8*)(&us[(rt * 16 + m) * 264 + kt * 32 + quad * 8]);
        f32x4 acc[2] = {z4, z4};
        #pragma unroll
        for (int kt = 0; kt < 8; ++kt)
            #pragma unroll
            for (int ct = 0; ct < 2; ++ct)
                acc[ct] = __builtin_amdgcn_mfma_f32_16x16x32_bf16(a[kt], b[ct][kt], acc[ct], 0, 0, 0);
        const int rowb = r0 + rt * 16 + quad * 4;
        #pragma unroll
        for (int ct = 0; ct < 2; ++ct) {
            const int col = w * 32 + ct * 16 + m;
            #pragma unroll
            for (int r = 0; r < 4; ++r) {
                const float val = acc[ct][r];
                if (rowb + r < NN) vb[(size_t)(rowb + r) * 128 + col] = f2bf(val);
                rs_[ct] += val; rq_[ct] += val * val;
            }
        }
    }
    #pragma unroll
    for (int ct = 0; ct < 2; ++ct) {
        float ss = rs_[ct], sq = rq_[ct];
        ss += __shfl_xor(ss, 16); ss += __shfl_xor(ss, 32);
        sq += __shfl_xor(sq, 16); sq += __shfl_xor(sq, 32);
        if (quad == 0) {
            const int col = w * 32 + ct * 16 + m;
            atomicAdd(&ps2[col], ss);
            atomicAdd(&pq2[col], sq);
        }
    }
}

// ---------------- BN2 + optional relu + residual (+ bf16 mirror), 8 ch/thread ----------------
__global__ void k_fin(const unsigned short* __restrict__ vb,
                      const float* __restrict__ ps2, const float* __restrict__ pq2,
                      const float* __restrict__ g2, const float* __restrict__ be2,
                      float* __restrict__ h, unsigned short* __restrict__ h_bf,
                      const int do_relu)
{
    __shared__ __align__(16) float scf[128], shf[128];
    const int tid = threadIdx.x;
    if (tid < 128) {
        const float mean = ps2[tid] * (1.0f / NN);
        const float var  = pq2[tid] * (1.0f / NN) - mean * mean;
        const float sc = g2[tid] * rsqrtf(var + 1e-5f);
        scf[tid] = sc;
        shf[tid] = be2[tid] - mean * sc;
    }
    __syncthreads();
    const int t = blockIdx.x * 256 + tid;   // grid exactly N*128/8
    const int base = t * 8;
    const int c = base & 127;
    union { bf16x8 v; unsigned short u[8]; } in, ob;
    in.v = *(const bf16x8*)(vb + base);
    const float4 s0 = *(const float4*)(scf + c), s1 = *(const float4*)(scf + c + 4);
    const float4 b0 = *(const float4*)(shf + c), b1 = *(const float4*)(shf + c + 4);
    float4 h0 = *(const float4*)(h + base), h1 = *(const float4*)(h + base + 4);
    float z;
    z = bf2f(in.u[0])*s0.x + b0.x; if (do_relu) z = z > 0.f ? z : 0.f; h0.x += z;
    z = bf2f(in.u[1])*s0.y + b0.y; if (do_relu) z = z > 0.f ? z : 0.f; h0.y += z;
    z = bf2f(in.u[2])*s0.z + b0.z; if (do_relu) z = z > 0.f ? z : 0.f; h0.z += z;
    z = bf2f(in.u[3])*s0.w + b0.w; if (do_relu) z = z > 0.f ? z : 0.f; h0.w += z;
    z = bf2f(in.u[4])*s1.x + b1.x; if (do_relu) z = z > 0.f ? z : 0.f; h1.x += z;
    z = bf2f(in.u[5])*s1.y + b1.y; if (do_relu) z = z > 0.f ? z : 0.f; h1.y += z;
    z = bf2f(in.u[6])*s1.z + b1.z; if (do_relu) z = z > 0.f ? z : 0.f; h1.z += z;
    z = bf2f(in.u[7])*s1.w + b1.w; if (do_relu) z = z > 0.f ? z : 0.f; h1.w += z;
    *(float4*)(h + base) = h0;
    *(float4*)(h + base + 4) = h1;
    ob.u[0]=f2bf(h0.x); ob.u[1]=f2bf(h0.y); ob.u[2]=f2bf(h0.z); ob.u[3]=f2bf(h0.w);
    ob.u[4]=f2bf(h1.x); ob.u[5]=f2bf(h1.y); ob.u[6]=f2bf(h1.z); ob.u[7]=f2bf(h1.w);
    *(bf16x8*)(h_bf + base) = ob.v;
}

extern "C" void kernel_launch(void* const* d_in, const int* in_sizes, int n_in,
                              void* d_out, int out_size, void* d_ws, size_t ws_size,
                              hipStream_t stream)
{
    const float* x       = (const float*)d_in[0];
    const int*   ei      = (const int*)  d_in[1];
    const float* ea      = (const float*)d_in[2];
    const float* W_node  = (const float*)d_in[3];
    const float* b_node  = (const float*)d_in[4];
    const float* We      = (const float*)d_in[5];
    const float* be      = (const float*)d_in[6];
    const float* eps_gin = (const float*)d_in[7];
    const float* W1      = (const float*)d_in[8];
    // d_in[9] = b1: cancels exactly under BN1 (mean subtraction)
    const float* g1      = (const float*)d_in[10];
    const float* beta1   = (const float*)d_in[11];
    const float* W2      = (const float*)d_in[12];
    // d_in[13] = b2: cancels exactly under BN2
    const float* g_bn    = (const float*)d_in[14];
    const float* beta_bn = (const float*)d_in[15];

    float* h = (float*)d_out;

    char* W = (char*)d_ws;
    int*   counts   = (int*)  (W + 0);             // 200000 B (also fill cursor)
    int*   row_ptr  = (int*)  (W + 200000);        // 200004 B → pad to 400064
    float* stats    = (float*)(W + 400064);        // 768 floats = 3072 B
    float* ps1 = stats, *pq1 = stats + 256, *ps2 = stats + 512, *pq2 = stats + 640;
    int*   src_perm = (int*)  (W + 403136);        // (EE+16)*4 = 3200064 B → 3603200
    int2*  esrc     = (int2*) (W + 3603200);       // (EE+8)*8 = 6400064 B → 10003264
    unsigned int* ea_h   = (unsigned int*)(W + 10003264);   // EE*32+512 = 25600512 B → 35603776
    unsigned short* Wp1  = (unsigned short*)(W + 35603776); // 327680 B → 35931456
    unsigned short* Wp2  = (unsigned short*)(W + 35931456); // 327680 B → 36259136
    unsigned short* z_bf = (unsigned short*)(W + 36259136); // 12800000 B (vb alias) → 49059136
    unsigned short* t_bf = (unsigned short*)(W + 49059136); // 25600000 B → 74659136
    unsigned short* h_bf = (unsigned short*)(W + 74659136); // 12800000 B → total ~87.5 MB
    unsigned short* vb   = z_bf;  // safe alias: z_bf dead after gemmB, vb born in gemmD

    (void)hipMemsetAsync(counts, 0, 200000, stream);
    (void)hipMemsetAsync(src_perm + EE, 0, 64, stream);   // pipeline overrun pad

    k_node_enc<<<dim3(NN * DD / 256), dim3(256), 0, stream>>>(x, W_node, b_node, h, h_bf);
    k_count<<<dim3(EE / 256), dim3(256), 0, stream>>>(ei, counts);
    k_scan<<<dim3(1), dim3(1024), 0, stream>>>(counts, row_ptr);
    k_fill1<<<dim3(EE / 256), dim3(256), 0, stream>>>(ei, counts, esrc);
    k_fill2<<<dim3(EE / 256), dim3(256), 0, stream>>>(esrc, ea, src_perm, ea_h);
    k_pack<<<dim3(2 * LL * 32768 / 256), dim3(256), 0, stream>>>(W1, W2, Wp1, Wp2);

    for (int l = 0; l < LL; ++l) {
        k_agg<<<dim3(NN / 4), dim3(256), 0, stream>>>(
            h_bf, ea_h, We + (size_t)l * FF * DD, be + (size_t)l * DD,
            eps_gin, l, row_ptr, src_perm, z_bf, stats);
        k_gemmB<<<dim3(NB), dim3(256), 0, stream>>>(
            z_bf, Wp1 + (size_t)l * 32768, t_bf, ps1, pq1);
        k_gemmD<<<dim3(NB), dim3(256), 0, stream>>>(
            t_bf, ps1, pq1, g1 + (size_t)l * 256, beta1 + (size_t)l * 256,
            Wp2 + (size_t)l * 32768, vb, ps2, pq2);
        k_fin<<<dim3(NN * DD / 8 / 256), dim3(256), 0, stream>>>(
            vb, ps2, pq2, g_bn + (size_t)l * 128, beta_bn + (size_t)l * 128,
            h, h_bf, (l < LL - 1) ? 1 : 0);
    }
}